// Round 5
// baseline (57.893 us; speedup 1.0000x reference)
//
#include <hip/hip_runtime.h>
#include <hip/hip_bf16.h>
#include <math.h>

#define DIN 512
#define TT  512
#define BSZ 128

using bf16x8 = __attribute__((ext_vector_type(8))) short;
using f32x4  = __attribute__((ext_vector_type(4))) float;

static __device__ __forceinline__ unsigned short f2bf(float x) {
    __hip_bfloat16 h = __float2bfloat16(x);
    return *reinterpret_cast<unsigned short*>(&h);
}
static __device__ __forceinline__ unsigned int pack2(float a, float b) {
    return (unsigned int)f2bf(a) | ((unsigned int)f2bf(b) << 16);
}

// ws layout: Pgb bf16 [4 bg][32 p][512 s], then qb f32 [128]. Pre-scaled by 0.125.

__global__ __launch_bounds__(512) void pk_kernel(const float* __restrict__ Q,
                                                 const float* __restrict__ Wk,
                                                 const float* __restrict__ bk,
                                                 unsigned short* __restrict__ Pgb,
                                                 float* __restrict__ qb) {
    const int bid = blockIdx.x;   // [0,128) = bg*32 + p
    const int bg = bid >> 5;
    const int p  = bid & 31;
    const int h  = p >> 2;
    const int ua = p & 3;
    const int a_q = h >> 1;
    const int h_q = (4 * h + bg) & 7;
    const int ch_base = ua * 512 + h * 64;

    __shared__ float qv[64];
    const int tid = threadIdx.x;
    if (tid < 64) qv[tid] = Q[(a_q * 8 + h_q) * 64 + tid];
    __syncthreads();

    const int s = tid;            // 512 threads, one s each
    float acc = 0.f;
    #pragma unroll 8
    for (int d = 0; d < 64; ++d)
        acc += qv[d] * Wk[(size_t)(ch_base + d) * DIN + s];
    Pgb[(size_t)(bg * 32 + p) * 512 + s] = f2bf(acc * 0.125f);

    if (tid == 0) {
        float sum = 0.f;
        for (int d = 0; d < 64; ++d) sum += qv[d] * bk[ch_base + d];
        qb[bg * 32 + p] = sum * 0.125f;
    }
}

// One block per (b, j). scores[128 trow][32 p] = V[128x512] @ P^T via bf16 MFMA.
// 4 waves x (2 M x 2 N) 16x16 tiles, K-steps of 32, depth-2 global prefetch.
__global__ __launch_bounds__(256) void score_kernel(const float* __restrict__ v,
                                                    const unsigned short* __restrict__ Pgb,
                                                    const float* __restrict__ qb,
                                                    float* __restrict__ attn) {
    const int bid = blockIdx.x;   // b*4 + j
    const int b = bid >> 2;
    const int j = bid & 3;
    const int bg = b >> 5;
    const int tid = threadIdx.x;
    const int lane = tid & 63;
    const int w = tid >> 6;       // wave id: M rows w*32..w*32+31

    __shared__ char VtB[128 * 80];          // V tile [128 rows][32 k] bf16, 80 B stride
    __shared__ char PtB[32 * 1040];         // P full [32 p][512 k] bf16, 1040 B stride
    __shared__ float red2[4][2][4][2];      // [wave][nt][hsub][m,s]

    const float* vbase = v + ((size_t)b * TT + j * 128) * DIN;

    // ---- stage full P (bf16) once: 32 KB ----
    {
        const int p  = tid >> 3;
        const int sg = tid & 7;
        const uint4* src = (const uint4*)(Pgb + ((size_t)(bg * 32 + p) * 512)) + sg * 8;
        uint4* dst = (uint4*)(PtB + p * 1040 + sg * 128);
        #pragma unroll
        for (int q = 0; q < 8; ++q) dst[q] = src[q];
    }

    const float qv0 = qb[bg * 32 + (lane & 15)];
    const float qv1 = qb[bg * 32 + 16 + (lane & 15)];

    f32x4 acc[2][2];
    #pragma unroll
    for (int i = 0; i < 2; ++i)
        #pragma unroll
        for (int n = 0; n < 2; ++n)
            #pragma unroll
            for (int r = 0; r < 4; ++r) acc[i][n][r] = 0.f;

    const int srow  = tid >> 1;
    const int shalf = tid & 1;
    const float* vsrc = vbase + (size_t)srow * DIN + shalf * 16;
    char* vdst = VtB + srow * 80 + shalf * 32;

    const int akb = (lane >> 4) * 16;
    const char* aptr = VtB + (w * 32 + (lane & 15)) * 80 + akb;
    const char* bptr0 = PtB + ((lane & 15)) * 1040 + akb;
    const char* bptr1 = PtB + (16 + (lane & 15)) * 1040 + akb;

    // prologue: prefetch k-tiles 0 and 1
    float4 vrA[4], vrB[4];
    #pragma unroll
    for (int q = 0; q < 4; ++q) vrA[q] = *(const float4*)(vsrc + q * 4);
    #pragma unroll
    for (int q = 0; q < 4; ++q) vrB[q] = *(const float4*)(vsrc + 32 + q * 4);

#define SCORE_STEP(VR, KT)                                                    \
    {                                                                         \
        uint4 lo, hi;                                                         \
        lo.x = pack2(VR[0].x, VR[0].y); lo.y = pack2(VR[0].z, VR[0].w);       \
        lo.z = pack2(VR[1].x, VR[1].y); lo.w = pack2(VR[1].z, VR[1].w);       \
        hi.x = pack2(VR[2].x, VR[2].y); hi.y = pack2(VR[2].z, VR[2].w);       \
        hi.z = pack2(VR[3].x, VR[3].y); hi.w = pack2(VR[3].z, VR[3].w);       \
        *(uint4*)(vdst)      = lo;                                            \
        *(uint4*)(vdst + 16) = hi;                                            \
        __syncthreads();                                                      \
        if ((KT) < 14) {                                                      \
            const float* vn = vsrc + ((KT) + 2) * 32;                         \
            VR[0] = *(const float4*)(vn);                                     \
            VR[1] = *(const float4*)(vn + 4);                                 \
            VR[2] = *(const float4*)(vn + 8);                                 \
            VR[3] = *(const float4*)(vn + 12);                                \
        }                                                                     \
        const int ksb = (KT) * 64;                                            \
        bf16x8 a0 = *(const bf16x8*)(aptr);                                   \
        bf16x8 a1 = *(const bf16x8*)(aptr + 16 * 80);                         \
        bf16x8 b0 = *(const bf16x8*)(bptr0 + ksb);                            \
        bf16x8 b1 = *(const bf16x8*)(bptr1 + ksb);                            \
        acc[0][0] = __builtin_amdgcn_mfma_f32_16x16x32_bf16(a0, b0, acc[0][0], 0, 0, 0); \
        acc[0][1] = __builtin_amdgcn_mfma_f32_16x16x32_bf16(a0, b1, acc[0][1], 0, 0, 0); \
        acc[1][0] = __builtin_amdgcn_mfma_f32_16x16x32_bf16(a1, b0, acc[1][0], 0, 0, 0); \
        acc[1][1] = __builtin_amdgcn_mfma_f32_16x16x32_bf16(a1, b1, acc[1][1], 0, 0, 0); \
        __syncthreads();                                                      \
    }

    for (int kt = 0; kt < 16; kt += 2) {
        SCORE_STEP(vrA, kt);
        SCORE_STEP(vrB, kt + 1);
    }
#undef SCORE_STEP

    // ---- logits + per-h softmax ----
    float lg[2][8];
    #pragma unroll
    for (int i = 0; i < 2; ++i)
        #pragma unroll
        for (int r = 0; r < 4; ++r) {
            lg[0][i * 4 + r] = acc[i][0][r] + qv0;
            lg[1][i * 4 + r] = acc[i][1][r] + qv1;
        }

    const int hsub = (lane >> 2) & 3;
    float mw[2], sw[2], ev[2][8];
    #pragma unroll
    for (int nt = 0; nt < 2; ++nt) {
        float m = lg[nt][0];
        #pragma unroll
        for (int q = 1; q < 8; ++q) m = fmaxf(m, lg[nt][q]);
        m = fmaxf(m, __shfl_xor(m, 1));
        m = fmaxf(m, __shfl_xor(m, 2));
        m = fmaxf(m, __shfl_xor(m, 16));
        m = fmaxf(m, __shfl_xor(m, 32));
        float s = 0.f;
        #pragma unroll
        for (int q = 0; q < 8; ++q) { ev[nt][q] = __expf(lg[nt][q] - m); s += ev[nt][q]; }
        s += __shfl_xor(s, 1);
        s += __shfl_xor(s, 2);
        s += __shfl_xor(s, 16);
        s += __shfl_xor(s, 32);
        mw[nt] = m; sw[nt] = s;
    }
    if ((lane & 0x33) == 0) {
        #pragma unroll
        for (int nt = 0; nt < 2; ++nt) {
            red2[w][nt][hsub][0] = mw[nt];
            red2[w][nt][hsub][1] = sw[nt];
        }
    }
    __syncthreads();

    #pragma unroll
    for (int nt = 0; nt < 2; ++nt) {
        float M = red2[0][nt][hsub][0];
        M = fmaxf(M, red2[1][nt][hsub][0]);
        M = fmaxf(M, red2[2][nt][hsub][0]);
        M = fmaxf(M, red2[3][nt][hsub][0]);
        float S = 0.f;
        #pragma unroll
        for (int w2 = 0; w2 < 4; ++w2)
            S += __expf(red2[w2][nt][hsub][0] - M) * red2[w2][nt][hsub][1];
        const float factor = __expf(mw[nt] - M) / S;

        const int h = nt * 4 + hsub;
        float* arow = attn + ((size_t)(h * 512 + b * 4 + j)) * 512;
        const int ua = lane & 3;
        #pragma unroll
        for (int i = 0; i < 2; ++i)
            #pragma unroll
            for (int r = 0; r < 4; ++r) {
                const int trow = w * 32 + i * 16 + ((lane >> 4) & 3) * 4 + r;
                arow[trow * 4 + ua] = ev[nt][i * 4 + r] * factor;
            }
    }
}

// One block per (b, h): out[x=(h,b,j)][c] = sum_u attn[x][u] * v[b,u,h*64+c]
// depth-2 prefetch; at/red LDS union -> 35 KB -> 4 blocks/CU.
__global__ __launch_bounds__(256) void pv_kernel(const float* __restrict__ v,
                                                 const float* __restrict__ attn,
                                                 float* __restrict__ out) {
    const int bid = blockIdx.x;   // b*8 + h
    const int b = bid >> 3;
    const int h = bid & 7;
    const int tid = threadIdx.x;

    __shared__ __align__(16) char smem[34816];
    float (*at)[512]   = reinterpret_cast<float (*)[512]>(smem);    // [4][512] = 8 KB
    float (*red)[4][68] = reinterpret_cast<float (*)[4][68]>(smem); // [32][4][68] = 34816 B

    {   // stage attn rows for 4 j values (8 KB, coalesced)
        const int j  = tid >> 6;
        const int u8 = (tid & 63) * 8;
        const float* src = attn + ((size_t)(h * 512 + b * 4 + j)) * 512 + u8;
        *(float4*)&at[j][u8]     = *(const float4*)(src);
        *(float4*)&at[j][u8 + 4] = *(const float4*)(src + 4);
    }
    __syncthreads();

    const int cg = tid & 7;          // channel octet: c8 = cg*8
    const int up = tid >> 3;         // u phase [0,32)
    const int c8 = cg * 8;
    const float* vb = v + (size_t)b * TT * DIN + h * 64 + c8;

    float acc[4][8];
    #pragma unroll
    for (int jj = 0; jj < 4; ++jj)
        #pragma unroll
        for (int ci = 0; ci < 8; ++ci) acc[jj][ci] = 0.f;

    // depth-2 prologue: u = up and u = up+32 in flight
    float4 rA0 = *(const float4*)(vb + (size_t)up * DIN);
    float4 rA1 = *(const float4*)(vb + (size_t)up * DIN + 4);
    float4 rB0 = *(const float4*)(vb + (size_t)(up + 32) * DIN);
    float4 rB1 = *(const float4*)(vb + (size_t)(up + 32) * DIN + 4);

#define PV_STEP(R0, R1, IT)                                                   \
    {                                                                         \
        const int u = (IT) * 32 + up;                                         \
        const float4 c0 = R0;                                                 \
        const float4 c1 = R1;                                                 \
        if ((IT) < 14) {                                                      \
            const float* pn = vb + (size_t)(u + 64) * DIN;                    \
            R0 = *(const float4*)(pn);                                        \
            R1 = *(const float4*)(pn + 4);                                    \
        }                                                                     \
        const float a0 = at[0][u];                                            \
        const float a1 = at[1][u];                                            \
        const float a2 = at[2][u];                                            \
        const float a3 = at[3][u];                                            \
        acc[0][0] += a0 * c0.x; acc[0][1] += a0 * c0.y; acc[0][2] += a0 * c0.z; acc[0][3] += a0 * c0.w; \
        acc[0][4] += a0 * c1.x; acc[0][5] += a0 * c1.y; acc[0][6] += a0 * c1.z; acc[0][7] += a0 * c1.w; \
        acc[1][0] += a1 * c0.x; acc[1][1] += a1 * c0.y; acc[1][2] += a1 * c0.z; acc[1][3] += a1 * c0.w; \
        acc[1][4] += a1 * c1.x; acc[1][5] += a1 * c1.y; acc[1][6] += a1 * c1.z; acc[1][7] += a1 * c1.w; \
        acc[2][0] += a2 * c0.x; acc[2][1] += a2 * c0.y; acc[2][2] += a2 * c0.z; acc[2][3] += a2 * c0.w; \
        acc[2][4] += a2 * c1.x; acc[2][5] += a2 * c1.y; acc[2][6] += a2 * c1.z; acc[2][7] += a2 * c1.w; \
        acc[3][0] += a3 * c0.x; acc[3][1] += a3 * c0.y; acc[3][2] += a3 * c0.z; acc[3][3] += a3 * c0.w; \
        acc[3][4] += a3 * c1.x; acc[3][5] += a3 * c1.y; acc[3][6] += a3 * c1.z; acc[3][7] += a3 * c1.w; \
    }

    for (int it = 0; it < 16; it += 2) {
        PV_STEP(rA0, rA1, it);
        PV_STEP(rB0, rB1, it + 1);
    }
#undef PV_STEP

    __syncthreads();   // at[] dead beyond here; red aliases it

    #pragma unroll
    for (int jj = 0; jj < 4; ++jj) {
        float4 w0, w1;
        w0.x = acc[jj][0]; w0.y = acc[jj][1]; w0.z = acc[jj][2]; w0.w = acc[jj][3];
        w1.x = acc[jj][4]; w1.y = acc[jj][5]; w1.z = acc[jj][6]; w1.w = acc[jj][7];
        *(float4*)&red[up][jj][c8]     = w0;
        *(float4*)&red[up][jj][c8 + 4] = w1;
    }
    __syncthreads();

    const int jo = tid >> 6;
    const int c  = tid & 63;
    float s = 0.f;
    #pragma unroll
    for (int r2 = 0; r2 < 32; ++r2) s += red[r2][jo][c];
    out[((size_t)(h * 512 + b * 4 + jo)) * 64 + c] = s;
}

extern "C" void kernel_launch(void* const* d_in, const int* in_sizes, int n_in,
                              void* d_out, int out_size, void* d_ws, size_t ws_size,
                              hipStream_t stream) {
    const float* v  = (const float*)d_in[0];
    const float* Q  = (const float*)d_in[1];
    const float* Wk = (const float*)d_in[2];
    const float* bk = (const float*)d_in[3];

    float* out  = (float*)d_out;               // 4096*64
    float* attn = out + 4096 * 64;             // 4096*512

    unsigned short* Pgb = (unsigned short*)d_ws;     // 4*32*512 bf16
    float* qb = (float*)(Pgb + 4 * 32 * 512);        // 128 f32

    pk_kernel<<<128, 512, 0, stream>>>(Q, Wk, bk, Pgb, qb);
    score_kernel<<<512, 256, 0, stream>>>(v, Pgb, qb, attn);
    pv_kernel<<<1024, 256, 0, stream>>>(v, attn, out);
}